// Round 12
// baseline (2147.452 us; speedup 1.0000x reference)
//
#include <hip/hip_runtime.h>
#include <stdint.h>

typedef unsigned short u16;
typedef __attribute__((ext_vector_type(8))) short short8;
typedef __attribute__((ext_vector_type(4))) float f32x4;

#define KGU  5120
#define NPD  2560
#define KD   27648
#define SPLITD 12
#define KCHD 2304            // 27648/12
#define PEL (256*2560)

__device__ __forceinline__ uint32_t f2bf(float x) {
  uint32_t b = __float_as_uint(x);
  return (b + 0x7fffu + ((b >> 16) & 1u)) >> 16;
}
__device__ __forceinline__ uint32_t pk2(float lo, float hi) { return f2bf(lo) | (f2bf(hi) << 16); }
__device__ __forceinline__ uint32_t cvtpk(float lo, float hi) {
  uint32_t r;
  asm("v_cvt_pk_bf16_f32 %0, %1, %2" : "=v"(r) : "v"(lo), "v"(hi));
  return r;
}
__device__ __forceinline__ float silu(float x) {
  return x * __builtin_amdgcn_rcpf(1.f + __expf(-x));
}
#define MFMA16(a,b,c) __builtin_amdgcn_mfma_f32_16x16x32_bf16(a, b, c, 0, 0, 0)

// ---------------- kernel 0: x fp32 -> XF bf16, MFMA-fragment order ----------------
__global__ __launch_bounds__(256) void k_cvt(const float* __restrict__ X, u16* __restrict__ XF) {
  const int kt = blockIdx.x;
  const int lane = threadIdx.x & 63, wv = threadIdx.x >> 6;
#pragma unroll
  for (int ii = 0; ii < 4; ++ii) {
    const int mt = wv * 4 + ii;
    const float* src = X + (size_t)(mt * 16 + (lane & 15)) * KGU + kt * 32 + (lane >> 4) * 8;
    float4 f0 = *(const float4*)src;
    float4 f1 = *(const float4*)(src + 4);
    uint4 v;
    v.x = cvtpk(f0.x, f0.y); v.y = cvtpk(f0.z, f0.w);
    v.z = cvtpk(f1.x, f1.y); v.w = cvtpk(f1.z, f1.w);
    *(uint4*)(XF + ((size_t)(kt * 16 + mt) * 64 + lane) * 8) = v;
  }
}

// ---------------- kernel 1: gate+up GEMM — high-TLP small blocks ----------------
// 256 thr / 4 waves. Tile M=64 x 32 pairs (64 interleaved cols). Grid 1728 (432 j x 4 m).
// Wave = 16-token m-frag x 64 cols: per kt {1 A-frag global (1KB contig, L2), 4 B ds_read_b128,
// 4 MFMA}. B: SK=64 supertile, 4x float4/thread (256B contig/row), dist-2 reg prefetch,
// cvt_pk once -> XOR-granule LDS dbuf (2x8KB). One 4-wave s_barrier per supertile.
__global__ __launch_bounds__(256, 6)
void k_gu(const u16* __restrict__ XF,
          const float* __restrict__ Wg, const float* __restrict__ bg,
          const float* __restrict__ W1g, const float* __restrict__ b1g,
          const float* __restrict__ W2g, const float* __restrict__ b2g,
          const float* __restrict__ Wu, const float* __restrict__ bu,
          const float* __restrict__ W1u, const float* __restrict__ b1u,
          const float* __restrict__ W2u, const float* __restrict__ b2u,
          u16* __restrict__ HF) {
  __shared__ __align__(16) char smem[16384 + 1536];
  const int tid = threadIdx.x, lane = tid & 63, wv = tid >> 6;
  const int s_ = lane & 15, quad = lane >> 4;
  const int mq = blockIdx.x & 3;                 // m-quarter (64 tokens)
  const int j0p = (blockIdx.x >> 2) * 32;        // 32 channel-pairs

  float4* mc4 = (float4*)(smem + 16384);
  float*  mc1s = (float*)(smem + 16384 + 1024);
  if (tid < 64) {
    int sel = tid >> 5, m = tid & 31;
    const float* w1 = (sel ? W1u : W1g) + m * 6;
    const float* b1 = sel ? b1u : b1g;
    const float* w2 = sel ? W2u : W2g;
    mc4[sel * 32 + m] = make_float4(w1[0] + w1[2] + w1[4], w1[1] + w1[3] + w1[5], b1[m], w2[m]);
    mc1s[sel * 32 + m] = w2[32 + m];
  }

  // B staging: thread -> 4 rows r_i = (tid>>4) + 16*i, col-chunk c = tid&15 (float4).
  // Row r: even -> Wg[j0p+r/2], odd -> Wu[j0p+r/2]. 16 thr/row = 256B contiguous.
  const int r0 = tid >> 4, cc = tid & 15;
  const float* srcW[4];
  int wadr[4];
#pragma unroll
  for (int i = 0; i < 4; ++i) {
    const int r = r0 + 16 * i;
    srcW[i] = ((r & 1) ? Wu : Wg) + (size_t)(j0p + (r >> 1)) * KGU + cc * 4;
    wadr[i] = r * 128 + (((cc >> 1) ^ (r & 7)) << 4) + (cc & 1) * 8;
  }

  // A fragment base: wave owns global m-frag mt = mq*4 + wv
  const short8* pa = (const short8*)XF + ((size_t)(mq * 4 + wv)) * 64 + lane;

  // B-frag read offsets: row = ni*16+s_, granule g = kt2*4+quad, swizzled
  int roff[4];
#pragma unroll
  for (int ni = 0; ni < 4; ++ni) {
    const int row = ni * 16 + s_;
    roff[ni] = row * 128 + (((quad) ^ (row & 7)) << 4);   // kt2=0; kt2=1 adds XOR of 4
  }
  const int g1x = 4 << 4;  // granule +4 => XOR bit (since (g^r)&4 flips with g's bit2)

  f32x4 acc[4];
#pragma unroll
  for (int i = 0; i < 4; ++i) acc[i] = (f32x4)0.f;

  float4 W0[4], W1r[4];
  short8 A0, A1;

  auto loadW = [&](float4* W, int st) {
#pragma unroll
    for (int i = 0; i < 4; ++i) W[i] = *(const float4*)(srcW[i] + st * 64);
  };
  auto stageW = [&](float4* W, char* buf) {
#pragma unroll
    for (int i = 0; i < 4; ++i) {
      uint2 v;
      v.x = cvtpk(W[i].x, W[i].y); v.y = cvtpk(W[i].z, W[i].w);
      *(uint2*)(buf + wadr[i]) = v;
    }
  };

  // prologue
  loadW(W0, 0);
  loadW(W1r, 1);
  A0 = pa[0]; A1 = pa[16 * 64];
  stageW(W0, smem);                  // waits W0 (counted vmcnt), W1r/A stay in flight
  loadW(W0, 2);
  asm volatile("s_waitcnt lgkmcnt(0)" ::: "memory");
  __builtin_amdgcn_sched_barrier(0);
  __builtin_amdgcn_s_barrier();

#pragma unroll 1
  for (int st = 0; st < 80; ++st) {
    const char* buf = smem + (st & 1) * 8192;
    const int k0 = 2 * st;
    // kt even
    {
      short8 b0 = *(const short8*)(buf + roff[0]);
      short8 b1 = *(const short8*)(buf + roff[1]);
      short8 b2 = *(const short8*)(buf + roff[2]);
      short8 b3 = *(const short8*)(buf + roff[3]);
      int kn = k0 + 2; if (kn > 159) kn = 159;
      short8 An = pa[(size_t)kn * 1024];           // reload A0 (dist-2 kt)
      __builtin_amdgcn_s_setprio(1);
      acc[0] = MFMA16(A0, b0, acc[0]);
      acc[1] = MFMA16(A0, b1, acc[1]);
      acc[2] = MFMA16(A0, b2, acc[2]);
      acc[3] = MFMA16(A0, b3, acc[3]);
      __builtin_amdgcn_s_setprio(0);
      A0 = An;
    }
    // kt odd
    {
      short8 b0 = *(const short8*)(buf + (roff[0] ^ g1x));
      short8 b1 = *(const short8*)(buf + (roff[1] ^ g1x));
      short8 b2 = *(const short8*)(buf + (roff[2] ^ g1x));
      short8 b3 = *(const short8*)(buf + (roff[3] ^ g1x));
      int kn = k0 + 3; if (kn > 159) kn = 159;
      short8 An = pa[(size_t)kn * 1024];
      __builtin_amdgcn_s_setprio(1);
      acc[0] = MFMA16(A1, b0, acc[0]);
      acc[1] = MFMA16(A1, b1, acc[1]);
      acc[2] = MFMA16(A1, b2, acc[2]);
      acc[3] = MFMA16(A1, b3, acc[3]);
      __builtin_amdgcn_s_setprio(0);
      A1 = An;
    }
    if (st < 79) {
      char* bufn = smem + ((st + 1) & 1) * 8192;
      float4* Wst = ((st + 1) & 1) ? W1r : W0;     // set holding supertile st+1
      stageW(Wst, bufn);
      int stf = st + 3; if (stf > 79) stf = 79;    // refill same-parity set
      loadW(Wst, stf);
      asm volatile("s_waitcnt lgkmcnt(0)" ::: "memory");
      __builtin_amdgcn_sched_barrier(0);
      __builtin_amdgcn_s_barrier();
    }
  }

  // ---- fused epilogue: qrun per lane (gate even / up odd), shfl pair, silu*up -> HF ----
  const int sel = lane & 1;
  const float b2v0 = sel ? b2u[0] : b2g[0];
  const float b2v1 = sel ? b2u[1] : b2g[1];
  const float4* mcs = mc4 + sel * 32;
  const float*  mcw = mc1s + sel * 32;
  char* HFb = (char*)HF;
  const int mt2 = mq * 4 + wv;
#pragma unroll
  for (int ni = 0; ni < 4; ++ni) {
    const int c = ni * 16 + s_;
    const int j = j0p + (c >> 1);
    const float bp = sel ? bu[j] : bg[j];
    float sv[4], cvv[4], o0[4], o1[4];
#pragma unroll
    for (int e = 0; e < 4; ++e) {
      float p = acc[ni][e] + bp;
      sv[e] = __sinf(p); cvv[e] = __cosf(p);
      o0[e] = b2v0; o1[e] = b2v1;
    }
#pragma unroll 4
    for (int m = 0; m < 32; ++m) {
      float4 k4 = mcs[m]; float w2b = mcw[m];
#pragma unroll
      for (int e = 0; e < 4; ++e) {
        float hh = fmaxf(fmaf(sv[e], k4.x, fmaf(cvv[e], k4.y, k4.z)), 0.f);
        o0[e] = fmaf(hh, k4.w, o0[e]);
        o1[e] = fmaf(hh, w2b, o1[e]);
      }
    }
#pragma unroll
    for (int e = 0; e < 4; ++e) {
      float t0 = __shfl_xor(o0[e], 1);
      float t1 = __shfl_xor(o1[e], 1);
      float g0 = sel ? t0 : o0[e];
      float u0 = sel ? o0[e] : t0;
      float g1 = sel ? t1 : o1[e];
      float u1 = sel ? o1[e] : t1;
      float h0 = silu(g0) * u0, h1 = silu(g1) * u1;
      if (!sel) {
        const int kt2 = j >> 4;
        const int lf2 = (quad * 4 + e) + 16 * ((j >> 2) & 3);
        *(uint32_t*)(HFb + ((size_t)(kt2 * 16 + mt2) * 64 + lf2) * 16 + (j & 3) * 4)
            = pk2(h0, h1);
      }
    }
  }
}

// ---------------- kernel 2: down GEMM — same template, splitK=12 ----------------
// Tile M=64 x N=64, SK=64 (36 supertiles of KCHD=2304). Grid 1920 (4m x 40n x 12sk).
__global__ __launch_bounds__(256, 6)
void k_down(const u16* __restrict__ HF, const float* __restrict__ Wd, float* __restrict__ P2) {
  __shared__ __align__(16) char smem[16384];
  const int tid = threadIdx.x, lane = tid & 63, wv = tid >> 6;
  const int s_ = lane & 15, quad = lane >> 4;
  const int mq = blockIdx.x & 3;
  const int rest = blockIdx.x >> 2;
  const int nt = rest % 40, sk = rest / 40;
  const int n0 = nt * 64;

  const int r0 = tid >> 4, cc = tid & 15;
  const float* srcW[4];
  int wadr[4];
#pragma unroll
  for (int i = 0; i < 4; ++i) {
    const int r = r0 + 16 * i;
    srcW[i] = Wd + (size_t)(n0 + r) * KD + sk * KCHD + cc * 4;
    wadr[i] = r * 128 + (((cc >> 1) ^ (r & 7)) << 4) + (cc & 1) * 8;
  }

  const short8* pa = (const short8*)HF + ((size_t)(sk * 72) * 16 + mq * 4 + wv) * 64 + lane;

  int roff[4];
#pragma unroll
  for (int ni = 0; ni < 4; ++ni) {
    const int row = ni * 16 + s_;
    roff[ni] = row * 128 + (((quad) ^ (row & 7)) << 4);
  }
  const int g1x = 4 << 4;

  f32x4 acc[4];
#pragma unroll
  for (int i = 0; i < 4; ++i) acc[i] = (f32x4)0.f;

  float4 W0[4], W1r[4];
  short8 A0, A1;

  auto loadW = [&](float4* W, int st) {
#pragma unroll
    for (int i = 0; i < 4; ++i) W[i] = *(const float4*)(srcW[i] + st * 64);
  };
  auto stageW = [&](float4* W, char* buf) {
#pragma unroll
    for (int i = 0; i < 4; ++i) {
      uint2 v;
      v.x = cvtpk(W[i].x, W[i].y); v.y = cvtpk(W[i].z, W[i].w);
      *(uint2*)(buf + wadr[i]) = v;
    }
  };

  loadW(W0, 0);
  loadW(W1r, 1);
  A0 = pa[0]; A1 = pa[16 * 64];
  stageW(W0, smem);
  loadW(W0, 2);
  asm volatile("s_waitcnt lgkmcnt(0)" ::: "memory");
  __builtin_amdgcn_sched_barrier(0);
  __builtin_amdgcn_s_barrier();

#pragma unroll 1
  for (int st = 0; st < 36; ++st) {
    const char* buf = smem + (st & 1) * 8192;
    const int k0 = 2 * st;
    {
      short8 b0 = *(const short8*)(buf + roff[0]);
      short8 b1 = *(const short8*)(buf + roff[1]);
      short8 b2 = *(const short8*)(buf + roff[2]);
      short8 b3 = *(const short8*)(buf + roff[3]);
      int kn = k0 + 2; if (kn > 71) kn = 71;
      short8 An = pa[(size_t)kn * 1024];
      __builtin_amdgcn_s_setprio(1);
      acc[0] = MFMA16(A0, b0, acc[0]);
      acc[1] = MFMA16(A0, b1, acc[1]);
      acc[2] = MFMA16(A0, b2, acc[2]);
      acc[3] = MFMA16(A0, b3, acc[3]);
      __builtin_amdgcn_s_setprio(0);
      A0 = An;
    }
    {
      short8 b0 = *(const short8*)(buf + (roff[0] ^ g1x));
      short8 b1 = *(const short8*)(buf + (roff[1] ^ g1x));
      short8 b2 = *(const short8*)(buf + (roff[2] ^ g1x));
      short8 b3 = *(const short8*)(buf + (roff[3] ^ g1x));
      int kn = k0 + 3; if (kn > 71) kn = 71;
      short8 An = pa[(size_t)kn * 1024];
      __builtin_amdgcn_s_setprio(1);
      acc[0] = MFMA16(A1, b0, acc[0]);
      acc[1] = MFMA16(A1, b1, acc[1]);
      acc[2] = MFMA16(A1, b2, acc[2]);
      acc[3] = MFMA16(A1, b3, acc[3]);
      __builtin_amdgcn_s_setprio(0);
      A1 = An;
    }
    if (st < 35) {
      char* bufn = smem + ((st + 1) & 1) * 8192;
      float4* Wst = ((st + 1) & 1) ? W1r : W0;
      stageW(Wst, bufn);
      int stf = st + 3; if (stf > 35) stf = 35;
      loadW(Wst, stf);
      asm volatile("s_waitcnt lgkmcnt(0)" ::: "memory");
      __builtin_amdgcn_sched_barrier(0);
      __builtin_amdgcn_s_barrier();
    }
  }

  float* P = P2 + (size_t)sk * PEL;
  const int rowb = mq * 64 + wv * 16 + (quad << 2);
#pragma unroll
  for (int ni = 0; ni < 4; ++ni) {
    const int n = n0 + ni * 16 + s_;
#pragma unroll
    for (int e = 0; e < 4; ++e)
      P[(size_t)(rowb + e) * NPD + n] = acc[ni][e];
  }
}

// ---------------- kernel 3: reduce partials + QRUN-d epilogue -> out fp32 ----------------
__global__ __launch_bounds__(256) void k_fin(const float* __restrict__ P2, const float* __restrict__ bd,
    const float* __restrict__ W1d, const float* __restrict__ b1d, const float* __restrict__ W2d,
    const float* __restrict__ b2d, float* __restrict__ out) {
  __shared__ float4 mc0[32];
  __shared__ float mc1[32];
  const int tid = threadIdx.x;
  if (tid < 32) {
    const float* w = W1d + tid * 6;
    mc0[tid] = make_float4(w[0] + w[2] + w[4], w[1] + w[3] + w[5], b1d[tid], W2d[tid]);
    mc1[tid] = W2d[32 + tid];
  }
  __syncthreads();
  const int idx = blockIdx.x * 256 + tid;
  const int m = idx / NPD, j = idx - m * NPD;
  float p = bd[j];
#pragma unroll
  for (int sk = 0; sk < SPLITD; ++sk) p += P2[(size_t)sk * PEL + idx];
  float s = __sinf(p), c = __cosf(p);
  float o0 = b2d[0], o1 = b2d[1];
#pragma unroll 4
  for (int mm = 0; mm < 32; ++mm) {
    float4 k = mc0[mm];
    float hh = fmaxf(fmaf(s, k.x, fmaf(c, k.y, k.z)), 0.f);
    o0 = fmaf(hh, k.w, o0);
    o1 = fmaf(hh, mc1[mm], o1);
  }
  *(float2*)&out[(size_t)m * 5120 + 2 * j] = make_float2(o0, o1);
}

extern "C" void kernel_launch(void* const* d_in, const int* in_sizes, int n_in,
                              void* d_out, int out_size, void* d_ws, size_t ws_size,
                              hipStream_t stream) {
  const float* x   = (const float*)d_in[0];
  const float* Wg  = (const float*)d_in[1];
  const float* bg  = (const float*)d_in[2];
  const float* W1g = (const float*)d_in[3];
  const float* b1g = (const float*)d_in[4];
  const float* W2g = (const float*)d_in[5];
  const float* b2g = (const float*)d_in[6];
  const float* Wu  = (const float*)d_in[7];
  const float* bu  = (const float*)d_in[8];
  const float* W1u = (const float*)d_in[9];
  const float* b1u = (const float*)d_in[10];
  const float* W2u = (const float*)d_in[11];
  const float* b2u = (const float*)d_in[12];
  const float* Wd  = (const float*)d_in[13];
  const float* bd  = (const float*)d_in[14];
  const float* W1d = (const float*)d_in[15];
  const float* b1d = (const float*)d_in[16];
  const float* W2d = (const float*)d_in[17];
  const float* b2d = (const float*)d_in[18];
  char* ws = (char*)d_ws;
  u16*  XF = (u16*)ws;                     // 2,621,440 B
  u16*  HF = (u16*)(ws + 2621440);         // 14,155,776 B (ends 16,777,216)
  float* P2 = (float*)(ws + 16777216);     // 31,457,280 B
  if (ws_size < 48234496u) return;

  k_cvt<<<dim3(160), dim3(256), 0, stream>>>(x, XF);
  k_gu<<<dim3(1728), dim3(256), 0, stream>>>(XF, Wg, bg, W1g, b1g, W2g, b2g,
                                             Wu, bu, W1u, b1u, W2u, b2u, HF);
  k_down<<<dim3(1920), dim3(256), 0, stream>>>(HF, Wd, P2);
  k_fin<<<dim3(2560), dim3(256), 0, stream>>>(P2, bd, W1d, b1d, W2d, b2d, (float*)d_out);
}

// Round 13
// 395.618 us; speedup vs baseline: 5.4281x; 5.4281x over previous
//
#include <hip/hip_runtime.h>
#include <stdint.h>

typedef unsigned short u16;
typedef __attribute__((ext_vector_type(8))) short short8;
typedef __attribute__((ext_vector_type(4))) float f32x4;

#define KGU  5120
#define NPD  2560
#define KD   27648
#define SPLITD 12
#define KCHD 2304            // 27648/12
#define PEL (256*2560)

__device__ __forceinline__ uint32_t f2bf(float x) {
  uint32_t b = __float_as_uint(x);
  return (b + 0x7fffu + ((b >> 16) & 1u)) >> 16;
}
__device__ __forceinline__ uint32_t pk2(float lo, float hi) { return f2bf(lo) | (f2bf(hi) << 16); }
__device__ __forceinline__ uint32_t cvtpk(float lo, float hi) {
  uint32_t r;
  asm("v_cvt_pk_bf16_f32 %0, %1, %2" : "=v"(r) : "v"(lo), "v"(hi));
  return r;
}
__device__ __forceinline__ float silu(float x) {
  return x * __builtin_amdgcn_rcpf(1.f + __expf(-x));
}
#define MFMA16(a,b,c) __builtin_amdgcn_mfma_f32_16x16x32_bf16(a, b, c, 0, 0, 0)

// ---------------- kernel 0: x fp32 -> XF bf16, MFMA-fragment order ----------------
__global__ __launch_bounds__(256) void k_cvt(const float* __restrict__ X, u16* __restrict__ XF) {
  const int kt = blockIdx.x;
  const int lane = threadIdx.x & 63, wv = threadIdx.x >> 6;
#pragma unroll
  for (int ii = 0; ii < 4; ++ii) {
    const int mt = wv * 4 + ii;
    const float* src = X + (size_t)(mt * 16 + (lane & 15)) * KGU + kt * 32 + (lane >> 4) * 8;
    float4 f0 = *(const float4*)src;
    float4 f1 = *(const float4*)(src + 4);
    uint4 v;
    v.x = cvtpk(f0.x, f0.y); v.y = cvtpk(f0.z, f0.w);
    v.z = cvtpk(f1.x, f1.y); v.w = cvtpk(f1.z, f1.w);
    *(uint4*)(XF + ((size_t)(kt * 16 + mt) * 64 + lane) * 8) = v;
  }
}

// ---------------- kernel 1: gate+up GEMM — B exactly once + copy-bench staging ----------------
// 512 thr / 8 waves. Block = ALL 256 tokens x 16 channel-pairs (32 interleaved cols). Grid 864.
// Wave = 32 tokens (2 m-frags) x 32 cols. SK=256 supertile (20 total, 1 barrier each).
// Staging: wave owns 4 weight rows; each global instr = 1KB contiguous of ONE row (copy-bench
// pattern); cvt_pk once -> granule-XOR LDS (perfectly bank-uniform), dbuf 2x16KB.
__global__ __launch_bounds__(512, 6)
void k_gu(const u16* __restrict__ XF,
          const float* __restrict__ Wg, const float* __restrict__ bg,
          const float* __restrict__ W1g, const float* __restrict__ b1g,
          const float* __restrict__ W2g, const float* __restrict__ b2g,
          const float* __restrict__ Wu, const float* __restrict__ bu,
          const float* __restrict__ W1u, const float* __restrict__ b1u,
          const float* __restrict__ W2u, const float* __restrict__ b2u,
          u16* __restrict__ HF) {
  __shared__ __align__(16) char smem[32768 + 1536];
  const int tid = threadIdx.x, lane = tid & 63, wid = tid >> 6;   // wid 0..7
  const int s_ = lane & 15, quad = lane >> 4;
  const int j0p = blockIdx.x * 16;               // 16 channel-pairs

  float4* mc4 = (float4*)(smem + 32768);
  float*  mc1s = (float*)(smem + 32768 + 1024);
  if (tid < 64) {
    int sel = tid >> 5, m = tid & 31;
    const float* w1 = (sel ? W1u : W1g) + m * 6;
    const float* b1 = sel ? b1u : b1g;
    const float* w2 = sel ? W2u : W2g;
    mc4[sel * 32 + m] = make_float4(w1[0] + w1[2] + w1[4], w1[1] + w1[3] + w1[5], b1[m], w2[m]);
    mc1s[sel * 32 + m] = w2[32 + m];
  }

  // staging: wave owns LDS rows r = 4*wid + i (row r <-> interleaved col r:
  // even -> Wg[j0p + r/2], odd -> Wu[j0p + r/2]). lane covers floats lane*4..lane*4+3.
  const float* srcW[4];
  int wadr[4];
#pragma unroll
  for (int i = 0; i < 4; ++i) {
    const int r = 4 * wid + i;
    srcW[i] = ((r & 1) ? Wu : Wg) + (size_t)(j0p + (r >> 1)) * KGU + lane * 4;
    wadr[i] = r * 512 + ((((lane >> 1)) ^ (r & 7)) << 4) + (lane & 1) * 8;
  }

  const short8* paF = (const short8*)XF + lane;  // + (kt*16+mt)*64
  const int mt0 = 2 * wid, mt1 = 2 * wid + 1;

  f32x4 acc[2][2];
  acc[0][0] = (f32x4)0.f; acc[0][1] = (f32x4)0.f;
  acc[1][0] = (f32x4)0.f; acc[1][1] = (f32x4)0.f;
  float4 Wreg[4];
  short8 A0[2], A1[2];

  auto loadS = [&](int st) {
#pragma unroll
    for (int i = 0; i < 4; ++i) Wreg[i] = *(const float4*)(srcW[i] + st * 256);
  };
  auto stageS = [&](char* buf) {
#pragma unroll
    for (int i = 0; i < 4; ++i) {
      uint2 v;
      v.x = cvtpk(Wreg[i].x, Wreg[i].y); v.y = cvtpk(Wreg[i].z, Wreg[i].w);
      *(uint2*)(buf + wadr[i]) = v;
    }
  };

  loadS(0);
  A0[0] = paF[(size_t)(0 * 16 + mt0) * 64]; A0[1] = paF[(size_t)(0 * 16 + mt1) * 64];
  A1[0] = paF[(size_t)(1 * 16 + mt0) * 64]; A1[1] = paF[(size_t)(1 * 16 + mt1) * 64];
  stageS(smem);
  loadS(1);
  asm volatile("s_waitcnt lgkmcnt(0)" ::: "memory");
  __builtin_amdgcn_sched_barrier(0);
  __builtin_amdgcn_s_barrier();
  __builtin_amdgcn_sched_barrier(0);

#pragma unroll 1
  for (int st = 0; st < 20; ++st) {
    const char* buf = smem + (st & 1) * 16384;
#pragma unroll
    for (int k2 = 0; k2 < 4; ++k2) {
      const int ge = st * 8 + 2 * k2;
      {  // even kt
        const int go = ((2 * k2) * 4 + quad) ^ (s_ & 7);
        short8 b0 = *(const short8*)(buf + s_ * 512 + (go << 4));
        short8 b1 = *(const short8*)(buf + (16 + s_) * 512 + (go << 4));
        __builtin_amdgcn_s_setprio(1);
        acc[0][0] = MFMA16(A0[0], b0, acc[0][0]);
        acc[0][1] = MFMA16(A0[0], b1, acc[0][1]);
        acc[1][0] = MFMA16(A0[1], b0, acc[1][0]);
        acc[1][1] = MFMA16(A0[1], b1, acc[1][1]);
        __builtin_amdgcn_s_setprio(0);
        int kn = ge + 2; if (kn > 159) kn = 159;
        A0[0] = paF[(size_t)(kn * 16 + mt0) * 64];
        A0[1] = paF[(size_t)(kn * 16 + mt1) * 64];
      }
      {  // odd kt
        const int go = ((2 * k2 + 1) * 4 + quad) ^ (s_ & 7);
        short8 b0 = *(const short8*)(buf + s_ * 512 + (go << 4));
        short8 b1 = *(const short8*)(buf + (16 + s_) * 512 + (go << 4));
        __builtin_amdgcn_s_setprio(1);
        acc[0][0] = MFMA16(A1[0], b0, acc[0][0]);
        acc[0][1] = MFMA16(A1[0], b1, acc[0][1]);
        acc[1][0] = MFMA16(A1[1], b0, acc[1][0]);
        acc[1][1] = MFMA16(A1[1], b1, acc[1][1]);
        __builtin_amdgcn_s_setprio(0);
        int kn = ge + 3; if (kn > 159) kn = 159;
        A1[0] = paF[(size_t)(kn * 16 + mt0) * 64];
        A1[1] = paF[(size_t)(kn * 16 + mt1) * 64];
      }
    }
    if (st < 19) {
      char* bufn = smem + ((st + 1) & 1) * 16384;
      stageS(bufn);                      // Wreg holds supertile st+1 (loaded 1 period ago)
      int stf = st + 2; if (stf > 19) stf = 19;
      loadS(stf);
      asm volatile("s_waitcnt lgkmcnt(0)" ::: "memory");
      __builtin_amdgcn_sched_barrier(0);
      __builtin_amdgcn_s_barrier();
      __builtin_amdgcn_sched_barrier(0);
    }
  }

  // ---- fused epilogue: qrun per lane (gate even / up odd), shfl pair, silu*up -> HF ----
  const int sel = lane & 1;
  const float b2v0 = sel ? b2u[0] : b2g[0];
  const float b2v1 = sel ? b2u[1] : b2g[1];
  const float4* mcs = mc4 + sel * 32;
  const float*  mcw = mc1s + sel * 32;
  char* HFb = (char*)HF;
#pragma unroll
  for (int mi = 0; mi < 2; ++mi) {
    const int mt2 = 2 * wid + mi;
#pragma unroll
    for (int cf = 0; cf < 2; ++cf) {
      const int c = cf * 16 + s_;
      const int j = j0p + (c >> 1);
      const float bp = sel ? bu[j] : bg[j];
      float sv[4], cvv[4], o0[4], o1[4];
#pragma unroll
      for (int e = 0; e < 4; ++e) {
        float p = acc[mi][cf][e] + bp;
        sv[e] = __sinf(p); cvv[e] = __cosf(p);
        o0[e] = b2v0; o1[e] = b2v1;
      }
#pragma unroll 4
      for (int m = 0; m < 32; ++m) {
        float4 k4 = mcs[m]; float w2b = mcw[m];
#pragma unroll
        for (int e = 0; e < 4; ++e) {
          float hh = fmaxf(fmaf(sv[e], k4.x, fmaf(cvv[e], k4.y, k4.z)), 0.f);
          o0[e] = fmaf(hh, k4.w, o0[e]);
          o1[e] = fmaf(hh, w2b, o1[e]);
        }
      }
#pragma unroll
      for (int e = 0; e < 4; ++e) {
        float t0 = __shfl_xor(o0[e], 1);
        float t1 = __shfl_xor(o1[e], 1);
        float g0 = sel ? t0 : o0[e];
        float u0 = sel ? o0[e] : t0;
        float g1 = sel ? t1 : o1[e];
        float u1 = sel ? o1[e] : t1;
        float h0 = silu(g0) * u0, h1 = silu(g1) * u1;
        if (!sel) {
          const int lf2 = (quad * 4 + e) + 16 * ((j >> 2) & 3);
          *(uint32_t*)(HFb + ((size_t)(blockIdx.x * 16 + mt2) * 64 + lf2) * 16 + (j & 3) * 4)
              = pk2(h0, h1);
        }
      }
    }
  }
}

// ---------------- kernel 2: down GEMM — same template, splitK=12 ----------------
// Block = 256 tokens x 32 cols, K-chunk 2304 (9 supertiles of 256). Grid 960 (sk outer).
__global__ __launch_bounds__(512, 6)
void k_down(const u16* __restrict__ HF, const float* __restrict__ Wd, float* __restrict__ P2) {
  __shared__ __align__(16) char smem[32768];
  const int tid = threadIdx.x, lane = tid & 63, wid = tid >> 6;
  const int s_ = lane & 15, quad = lane >> 4;
  const int sk = blockIdx.x / 80;
  const int nt = blockIdx.x - sk * 80;
  const int n0 = nt * 32;

  const float* srcW[4];
  int wadr[4];
#pragma unroll
  for (int i = 0; i < 4; ++i) {
    const int r = 4 * wid + i;
    srcW[i] = Wd + (size_t)(n0 + r) * KD + sk * KCHD + lane * 4;
    wadr[i] = r * 512 + ((((lane >> 1)) ^ (r & 7)) << 4) + (lane & 1) * 8;
  }

  const short8* paF = (const short8*)HF + lane;
  const int kbase = sk * 72;
  const int mt0 = 2 * wid, mt1 = 2 * wid + 1;

  f32x4 acc[2][2];
  acc[0][0] = (f32x4)0.f; acc[0][1] = (f32x4)0.f;
  acc[1][0] = (f32x4)0.f; acc[1][1] = (f32x4)0.f;
  float4 Wreg[4];
  short8 A0[2], A1[2];

  auto loadS = [&](int st) {
#pragma unroll
    for (int i = 0; i < 4; ++i) Wreg[i] = *(const float4*)(srcW[i] + st * 256);
  };
  auto stageS = [&](char* buf) {
#pragma unroll
    for (int i = 0; i < 4; ++i) {
      uint2 v;
      v.x = cvtpk(Wreg[i].x, Wreg[i].y); v.y = cvtpk(Wreg[i].z, Wreg[i].w);
      *(uint2*)(buf + wadr[i]) = v;
    }
  };

  loadS(0);
  A0[0] = paF[(size_t)((kbase + 0) * 16 + mt0) * 64];
  A0[1] = paF[(size_t)((kbase + 0) * 16 + mt1) * 64];
  A1[0] = paF[(size_t)((kbase + 1) * 16 + mt0) * 64];
  A1[1] = paF[(size_t)((kbase + 1) * 16 + mt1) * 64];
  stageS(smem);
  loadS(1);
  asm volatile("s_waitcnt lgkmcnt(0)" ::: "memory");
  __builtin_amdgcn_sched_barrier(0);
  __builtin_amdgcn_s_barrier();
  __builtin_amdgcn_sched_barrier(0);

#pragma unroll 1
  for (int st = 0; st < 9; ++st) {
    const char* buf = smem + (st & 1) * 16384;
#pragma unroll
    for (int k2 = 0; k2 < 4; ++k2) {
      const int ge = st * 8 + 2 * k2;
      {
        const int go = ((2 * k2) * 4 + quad) ^ (s_ & 7);
        short8 b0 = *(const short8*)(buf + s_ * 512 + (go << 4));
        short8 b1 = *(const short8*)(buf + (16 + s_) * 512 + (go << 4));
        __builtin_amdgcn_s_setprio(1);
        acc[0][0] = MFMA16(A0[0], b0, acc[0][0]);
        acc[0][1] = MFMA16(A0[0], b1, acc[0][1]);
        acc[1][0] = MFMA16(A0[1], b0, acc[1][0]);
        acc[1][1] = MFMA16(A0[1], b1, acc[1][1]);
        __builtin_amdgcn_s_setprio(0);
        int kn = ge + 2; if (kn > 71) kn = 71;
        A0[0] = paF[(size_t)((kbase + kn) * 16 + mt0) * 64];
        A0[1] = paF[(size_t)((kbase + kn) * 16 + mt1) * 64];
      }
      {
        const int go = ((2 * k2 + 1) * 4 + quad) ^ (s_ & 7);
        short8 b0 = *(const short8*)(buf + s_ * 512 + (go << 4));
        short8 b1 = *(const short8*)(buf + (16 + s_) * 512 + (go << 4));
        __builtin_amdgcn_s_setprio(1);
        acc[0][0] = MFMA16(A1[0], b0, acc[0][0]);
        acc[0][1] = MFMA16(A1[0], b1, acc[0][1]);
        acc[1][0] = MFMA16(A1[1], b0, acc[1][0]);
        acc[1][1] = MFMA16(A1[1], b1, acc[1][1]);
        __builtin_amdgcn_s_setprio(0);
        int kn = ge + 3; if (kn > 71) kn = 71;
        A1[0] = paF[(size_t)((kbase + kn) * 16 + mt0) * 64];
        A1[1] = paF[(size_t)((kbase + kn) * 16 + mt1) * 64];
      }
    }
    if (st < 8) {
      char* bufn = smem + ((st + 1) & 1) * 16384;
      stageS(bufn);
      int stf = st + 2; if (stf > 8) stf = 8;
      loadS(stf);
      asm volatile("s_waitcnt lgkmcnt(0)" ::: "memory");
      __builtin_amdgcn_sched_barrier(0);
      __builtin_amdgcn_s_barrier();
      __builtin_amdgcn_sched_barrier(0);
    }
  }

  float* P = P2 + (size_t)sk * PEL;
#pragma unroll
  for (int mi = 0; mi < 2; ++mi) {
    const int rowb = (2 * wid + mi) * 16 + (quad << 2);
#pragma unroll
    for (int cf = 0; cf < 2; ++cf) {
      const int n = n0 + cf * 16 + s_;
#pragma unroll
      for (int e = 0; e < 4; ++e)
        P[(size_t)(rowb + e) * NPD + n] = acc[mi][cf][e];
    }
  }
}

// ---------------- kernel 3: reduce partials + QRUN-d epilogue -> out fp32 ----------------
__global__ __launch_bounds__(256) void k_fin(const float* __restrict__ P2, const float* __restrict__ bd,
    const float* __restrict__ W1d, const float* __restrict__ b1d, const float* __restrict__ W2d,
    const float* __restrict__ b2d, float* __restrict__ out) {
  __shared__ float4 mc0[32];
  __shared__ float mc1[32];
  const int tid = threadIdx.x;
  if (tid < 32) {
    const float* w = W1d + tid * 6;
    mc0[tid] = make_float4(w[0] + w[2] + w[4], w[1] + w[3] + w[5], b1d[tid], W2d[tid]);
    mc1[tid] = W2d[32 + tid];
  }
  __syncthreads();
  const int idx = blockIdx.x * 256 + tid;
  const int m = idx / NPD, j = idx - m * NPD;
  float p = bd[j];
#pragma unroll
  for (int sk = 0; sk < SPLITD; ++sk) p += P2[(size_t)sk * PEL + idx];
  float s = __sinf(p), c = __cosf(p);
  float o0 = b2d[0], o1 = b2d[1];
#pragma unroll 4
  for (int mm = 0; mm < 32; ++mm) {
    float4 k = mc0[mm];
    float hh = fmaxf(fmaf(s, k.x, fmaf(c, k.y, k.z)), 0.f);
    o0 = fmaf(hh, k.w, o0);
    o1 = fmaf(hh, mc1[mm], o1);
  }
  *(float2*)&out[(size_t)m * 5120 + 2 * j] = make_float2(o0, o1);
}

extern "C" void kernel_launch(void* const* d_in, const int* in_sizes, int n_in,
                              void* d_out, int out_size, void* d_ws, size_t ws_size,
                              hipStream_t stream) {
  const float* x   = (const float*)d_in[0];
  const float* Wg  = (const float*)d_in[1];
  const float* bg  = (const float*)d_in[2];
  const float* W1g = (const float*)d_in[3];
  const float* b1g = (const float*)d_in[4];
  const float* W2g = (const float*)d_in[5];
  const float* b2g = (const float*)d_in[6];
  const float* Wu  = (const float*)d_in[7];
  const float* bu  = (const float*)d_in[8];
  const float* W1u = (const float*)d_in[9];
  const float* b1u = (const float*)d_in[10];
  const float* W2u = (const float*)d_in[11];
  const float* b2u = (const float*)d_in[12];
  const float* Wd  = (const float*)d_in[13];
  const float* bd  = (const float*)d_in[14];
  const float* W1d = (const float*)d_in[15];
  const float* b1d = (const float*)d_in[16];
  const float* W2d = (const float*)d_in[17];
  const float* b2d = (const float*)d_in[18];
  char* ws = (char*)d_ws;
  u16*  XF = (u16*)ws;                     // 2,621,440 B
  u16*  HF = (u16*)(ws + 2621440);         // 14,155,776 B (ends 16,777,216)
  float* P2 = (float*)(ws + 16777216);     // 31,457,280 B
  if (ws_size < 48234496u) return;

  k_cvt<<<dim3(160), dim3(256), 0, stream>>>(x, XF);
  k_gu<<<dim3(864), dim3(512), 0, stream>>>(XF, Wg, bg, W1g, b1g, W2g, b2g,
                                            Wu, bu, W1u, b1u, W2u, b2u, HF);
  k_down<<<dim3(960), dim3(512), 0, stream>>>(HF, Wd, P2);
  k_fin<<<dim3(2560), dim3(256), 0, stream>>>(P2, bd, W1d, b1d, W2d, b2d, (float*)d_out);
}